// Round 1
// baseline (349.325 us; speedup 1.0000x reference)
//
#include <hip/hip_runtime.h>
#include <hip/hip_bf16.h>
#include <math.h>

#define BB 4
#define NN 3000
#define FF 128
#define KP 3008   // K padded to multiple of 32 (MFMA K), pad rows zeroed

typedef __bf16 bf16x8 __attribute__((ext_vector_type(8)));
typedef __bf16 bf16x4 __attribute__((ext_vector_type(4)));
typedef float  f32x4  __attribute__((ext_vector_type(4)));

// ---------------- K1: dis[b*NN+i] = 1/sqrt(1 + sum_j adj[b,i,j]) ----------------
// one wave per row; 3000 floats = 750 float4 per row, coalesced.
__global__ __launch_bounds__(256) void k_deg(const float* __restrict__ adj,
                                             float* __restrict__ dis) {
    int wid  = (blockIdx.x * 256 + threadIdx.x) >> 6;   // global wave id = row id
    int lane = threadIdx.x & 63;
    if (wid >= BB * NN) return;
    const float4* row = (const float4*)(adj + (size_t)wid * NN);
    float s = 0.f;
    for (int c = lane; c < NN / 4; c += 64) {
        float4 v = row[c];
        s += (v.x + v.y) + (v.z + v.w);
    }
    for (int off = 32; off > 0; off >>= 1) s += __shfl_down(s, off, 64);
    if (lane == 0) dis[wid] = 1.0f / sqrtf(s + 1.0f);
}

// ---------------- K2: xst[b][f][j] = bf16(dis[b,j] * x[b,j,f]), zero-padded to KP ----
// 64-j x 128-f tile transposed through LDS; writes coalesced along j.
__global__ __launch_bounds__(256) void k_xst(const float* __restrict__ x,
                                             const float* __restrict__ dis,
                                             __bf16* __restrict__ xst) {
    __shared__ __bf16 tile[64][FF + 2];
    int b  = blockIdx.y;
    int j0 = blockIdx.x * 64;
    for (int idx = threadIdx.x; idx < 64 * FF; idx += 256) {
        int jj = idx >> 7, f = idx & 127;
        int j = j0 + jj;
        float v = 0.f;
        if (j < NN) v = dis[b * NN + j] * x[((size_t)b * NN + j) * FF + f];
        tile[jj][f] = (__bf16)v;
    }
    __syncthreads();
    int f  = threadIdx.x >> 1;
    int jp = (threadIdx.x & 1) * 32;
    __bf16* dst = xst + ((size_t)b * FF + f) * KP + j0 + jp;
    for (int q = 0; q < 32; ++q) dst[q] = tile[jp + q][f];
}

// ---------------- K3: support = (1-alpha)*hi + alpha*h0, hi = dis_i*(adj@xs + xs_i) ----
// Block: 16 output rows x 128 cols, 4 waves (wave w -> cols [32w,32w+32)).
// A (adj fp32) loaded straight from global, cvt to bf16; B from xst (B^T layout),
// both as 8 contiguous k per lane -> no LDS. Verified m92/m97 fragment pattern:
//   A[m=lane&15][k=quad*8+j], B^T[n=lane&15][k=quad*8+j], C: col=lane&15, row=quad*4+r.
__global__ __launch_bounds__(256) void k_agg(const float* __restrict__ adj,
                                             const float* __restrict__ x,
                                             const float* __restrict__ h0,
                                             const float* __restrict__ dis,
                                             const __bf16* __restrict__ xst,
                                             float* __restrict__ support,
                                             const float* __restrict__ alpha_p) {
    const int b    = blockIdx.y;
    const int i0   = blockIdx.x * 16;
    const int lane = threadIdx.x & 63;
    const int wave = threadIdx.x >> 6;
    const int m    = lane & 15;
    const int quad = lane >> 4;
    const int n0   = wave * 32;
    const int ra   = i0 + m;
    const bool rowok = ra < NN;
    const float*  arow = adj + ((size_t)b * NN + (rowok ? ra : 0)) * NN;
    const __bf16* xb0  = xst + ((size_t)b * FF + n0 + m) * KP;
    const __bf16* xb1  = xb0 + (size_t)16 * KP;
    f32x4 acc0 = {0.f, 0.f, 0.f, 0.f};
    f32x4 acc1 = {0.f, 0.f, 0.f, 0.f};
    #pragma unroll 4
    for (int k0 = 0; k0 < KP; k0 += 32) {
        int kb = k0 + quad * 8;
        bf16x8 a;
        if (rowok && kb < NN) {   // NN%8==0, so 8-chunk is all-in or all-out
            float4 u = *(const float4*)(arow + kb);
            float4 v = *(const float4*)(arow + kb + 4);
            a[0] = (__bf16)u.x; a[1] = (__bf16)u.y; a[2] = (__bf16)u.z; a[3] = (__bf16)u.w;
            a[4] = (__bf16)v.x; a[5] = (__bf16)v.y; a[6] = (__bf16)v.z; a[7] = (__bf16)v.w;
        } else {
            a[0]=a[1]=a[2]=a[3]=a[4]=a[5]=a[6]=a[7] = (__bf16)0.f;
        }
        bf16x8 b0 = *(const bf16x8*)(xb0 + kb);
        bf16x8 b1 = *(const bf16x8*)(xb1 + kb);
        acc0 = __builtin_amdgcn_mfma_f32_16x16x32_bf16(a, b0, acc0, 0, 0, 0);
        acc1 = __builtin_amdgcn_mfma_f32_16x16x32_bf16(a, b1, acc1, 0, 0, 0);
    }
    const float alpha = *alpha_p;
    #pragma unroll
    for (int r = 0; r < 4; ++r) {
        int irow = i0 + quad * 4 + r;
        if (irow < NN) {
            float  di   = dis[b * NN + irow];
            size_t base = ((size_t)b * NN + irow) * FF;
            int c0 = n0 + m;
            float hi0 = di * acc0[r] + di * di * x[base + c0];
            support[base + c0] = (1.f - alpha) * hi0 + alpha * h0[base + c0];
            int c1 = n0 + 16 + m;
            float hi1 = di * acc1[r] + di * di * x[base + c1];
            support[base + c1] = (1.f - alpha) * hi1 + alpha * h0[base + c1];
        }
    }
}

// ---------------- K4: out = beta*(support@theta) + (1-beta)*support ----------------
// Block: 16 rows x 128 cols. theta staged bf16 in LDS (32KB), support rows fp32 (8KB).
// Thread: 2 rows x 4 cols register block -> 3 LDS reads per 8 FMA.
__global__ __launch_bounds__(256) void k_out(const float* __restrict__ support,
                                             const float* __restrict__ theta,
                                             float* __restrict__ out,
                                             const float* __restrict__ lamda_p,
                                             const int* __restrict__ l_p) {
    __shared__ __bf16 th[FF * FF];
    __shared__ float  srow[16 * FF];
    int b  = blockIdx.y;
    int r0 = blockIdx.x * 16;
    for (int idx = threadIdx.x; idx < FF * FF; idx += 256) th[idx] = (__bf16)theta[idx];
    for (int idx = threadIdx.x; idx < 16 * FF; idx += 256) {
        int r = idx >> 7;
        int irow = r0 + r;
        srow[idx] = (irow < NN) ? support[((size_t)b * NN + irow) * FF + (idx & 127)] : 0.f;
    }
    __syncthreads();
    float beta = logf(*lamda_p / (float)(*l_p) + 1.0f);
    float omb  = 1.0f - beta;
    int c0 = (threadIdx.x & 31) * 4;
    int rp = (threadIdx.x >> 5) * 2;
    float a0[4] = {0.f, 0.f, 0.f, 0.f};
    float a1[4] = {0.f, 0.f, 0.f, 0.f};
    for (int g = 0; g < FF; ++g) {
        float s0 = srow[rp * FF + g];
        float s1 = srow[rp * FF + FF + g];
        bf16x4 t4 = *(const bf16x4*)&th[g * FF + c0];
        #pragma unroll
        for (int cc = 0; cc < 4; ++cc) {
            float tv = (float)t4[cc];
            a0[cc] += s0 * tv;
            a1[cc] += s1 * tv;
        }
    }
    int irow0 = r0 + rp;
    if (irow0 < NN) {
        float4 o;
        o.x = beta * a0[0] + omb * srow[rp * FF + c0 + 0];
        o.y = beta * a0[1] + omb * srow[rp * FF + c0 + 1];
        o.z = beta * a0[2] + omb * srow[rp * FF + c0 + 2];
        o.w = beta * a0[3] + omb * srow[rp * FF + c0 + 3];
        *(float4*)&out[((size_t)b * NN + irow0) * FF + c0] = o;
    }
    int irow1 = irow0 + 1;
    if (irow1 < NN) {
        float4 o;
        o.x = beta * a1[0] + omb * srow[(rp + 1) * FF + c0 + 0];
        o.y = beta * a1[1] + omb * srow[(rp + 1) * FF + c0 + 1];
        o.z = beta * a1[2] + omb * srow[(rp + 1) * FF + c0 + 2];
        o.w = beta * a1[3] + omb * srow[(rp + 1) * FF + c0 + 3];
        *(float4*)&out[((size_t)b * NN + irow1) * FF + c0] = o;
    }
}

extern "C" void kernel_launch(void* const* d_in, const int* in_sizes, int n_in,
                              void* d_out, int out_size, void* d_ws, size_t ws_size,
                              hipStream_t stream) {
    const float* x      = (const float*)d_in[0];
    const float* adj    = (const float*)d_in[1];
    const float* h0     = (const float*)d_in[2];
    const float* theta  = (const float*)d_in[3];
    const float* lamda  = (const float*)d_in[4];
    const float* alpha  = (const float*)d_in[5];
    const int*   l      = (const int*)d_in[6];
    float* out = (float*)d_out;

    char*   ws      = (char*)d_ws;
    float*  dis     = (float*)ws;                         // 48,000 B
    __bf16* xst     = (__bf16*)(ws + 65536);              // 3,080,192 B
    float*  support = (float*)(ws + 4 * 1024 * 1024);     // 6,144,000 B

    k_deg<<<dim3((BB * NN) / 4), 256, 0, stream>>>(adj, dis);
    k_xst<<<dim3(KP / 64, BB), 256, 0, stream>>>(x, dis, xst);
    k_agg<<<dim3((NN + 15) / 16, BB), 256, 0, stream>>>(adj, x, h0, dis, xst, support, alpha);
    k_out<<<dim3((NN + 15) / 16, BB), 256, 0, stream>>>(support, theta, out, lamda, l);
}

// Round 2
// 300.626 us; speedup vs baseline: 1.1620x; 1.1620x over previous
//
#include <hip/hip_runtime.h>
#include <hip/hip_bf16.h>
#include <math.h>

#define BB 4
#define NN 3000
#define FF 128
#define NKC 94          // number of 32-wide K chunks (94*32 = 3008 >= 3000)
#define NIT 188         // number of 16-row tiles (188*16 = 3008)

typedef __bf16 bf16x8 __attribute__((ext_vector_type(8)));
typedef __bf16 bf16x4 __attribute__((ext_vector_type(4)));
typedef float  f32x4  __attribute__((ext_vector_type(4)));

// ---------------- K1: dis[b*NN+i] = 1/sqrt(1 + sum_j adj[b,i,j]) ----------------
// one wave per row; coalesced float4 row reads.
__global__ __launch_bounds__(256) void k_deg(const float* __restrict__ adj,
                                             float* __restrict__ dis) {
    int wid  = (blockIdx.x * 256 + threadIdx.x) >> 6;
    int lane = threadIdx.x & 63;
    if (wid >= BB * NN) return;
    const float4* row = (const float4*)(adj + (size_t)wid * NN);
    float s = 0.f;
    for (int c = lane; c < NN / 4; c += 64) {
        float4 v = row[c];
        s += (v.x + v.y) + (v.z + v.w);
    }
    for (int off = 32; off > 0; off >>= 1) s += __shfl_down(s, off, 64);
    if (lane == 0) dis[wid] = 1.0f / sqrtf(s + 1.0f);
}

// ---------------- K2: pack xs = dis_k * x[k][f] into MFMA B-fragment order ------
// xpk[b][nt][kc][lane][8] with lane = (f%16) + 16*quad, element k = kc*32+quad*8+j.
// Writes: 16 B per lane, fully coalesced. Reads of x: 64 B segments (L2/L3-hot).
__global__ __launch_bounds__(256) void k_xpk(const float* __restrict__ x,
                                             const float* __restrict__ dis,
                                             __bf16* __restrict__ xpk) {
    int b  = blockIdx.y, kc = blockIdx.x;
    int t  = threadIdx.x, w = t >> 6, l = t & 63;
    int m  = l & 15, q = l >> 4;
    #pragma unroll
    for (int h = 0; h < 2; ++h) {
        int nt = w + h * 4;
        int f  = nt * 16 + m;
        bf16x8 v;
        #pragma unroll
        for (int j = 0; j < 8; ++j) {
            int k = kc * 32 + q * 8 + j;
            float val = 0.f;
            if (k < NN) val = dis[b * NN + k] * x[((size_t)b * NN + k) * FF + f];
            v[j] = (__bf16)val;
        }
        *(bf16x8*)(xpk + ((size_t)(b * 8 + nt) * NKC + kc) * 512 + l * 8) = v;
    }
}

// ---------------- K3: support = (1-alpha)*hi + alpha*h0 --------------------------
// hi_i = dis_i * (sum_j adj_ij * xs_j) + dis_i^2 * x_i   (self-loop folded out)
// Block: 16 rows x 128 cols, 4 waves. A staged via LDS (coalesced fp32 reads,
// bf16 convert once); B loaded as pre-packed coalesced fragment streams.
__global__ __launch_bounds__(256) void k_agg(const float* __restrict__ adj,
                                             const __bf16* __restrict__ xpk,
                                             const float* __restrict__ x,
                                             const float* __restrict__ h0,
                                             const float* __restrict__ dis,
                                             float* __restrict__ support,
                                             const float* __restrict__ alpha_p) {
    __shared__ __bf16 tile[16][264];   // 256-k chunk + 8 pad (conflict break)
    const int b  = blockIdx.y;
    const int it = blockIdx.x;
    const int i0 = it * 16;
    const int t  = threadIdx.x, w = t >> 6, l = t & 63;
    const int m  = l & 15, quad = l >> 4;
    const __bf16* B0 = xpk + ((size_t)(b * 8 + 2 * w) * NKC) * 512 + l * 8;
    const __bf16* B1 = B0 + (size_t)NKC * 512;
    f32x4 acc0 = {0.f, 0.f, 0.f, 0.f};
    f32x4 acc1 = {0.f, 0.f, 0.f, 0.f};
    for (int c = 0; c < 12; ++c) {
        int k0 = c * 256;
        #pragma unroll
        for (int i = 0; i < 4; ++i) {
            int row = i * 4 + w;
            int col = k0 + l * 4;
            float4 v = {0.f, 0.f, 0.f, 0.f};
            if (i0 + row < NN && col < NN)
                v = *(const float4*)(adj + ((size_t)b * NN + i0 + row) * NN + col);
            __bf16* tp = &tile[row][l * 4];
            tp[0] = (__bf16)v.x; tp[1] = (__bf16)v.y;
            tp[2] = (__bf16)v.z; tp[3] = (__bf16)v.w;
        }
        __syncthreads();
        int nk = (c == 11) ? 6 : 8;   // last chunk: k 2816..3007 -> 6 kc
        #pragma unroll 2
        for (int kcl = 0; kcl < nk; ++kcl) {
            int kc = c * 8 + kcl;
            bf16x8 a  = *(const bf16x8*)&tile[m][kcl * 32 + quad * 8];
            bf16x8 b0 = *(const bf16x8*)(B0 + (size_t)kc * 512);
            bf16x8 b1 = *(const bf16x8*)(B1 + (size_t)kc * 512);
            acc0 = __builtin_amdgcn_mfma_f32_16x16x32_bf16(a, b0, acc0, 0, 0, 0);
            acc1 = __builtin_amdgcn_mfma_f32_16x16x32_bf16(a, b1, acc1, 0, 0, 0);
        }
        __syncthreads();
    }
    const float alpha = *alpha_p;
    const int n0 = w * 32;
    #pragma unroll
    for (int r = 0; r < 4; ++r) {
        int irow = i0 + quad * 4 + r;
        if (irow < NN) {
            float  di   = dis[b * NN + irow];
            size_t base = ((size_t)b * NN + irow) * FF;
            int c0 = n0 + m;
            float hi0 = di * acc0[r] + di * di * x[base + c0];
            support[base + c0] = (1.f - alpha) * hi0 + alpha * h0[base + c0];
            int c1 = n0 + 16 + m;
            float hi1 = di * acc1[r] + di * di * x[base + c1];
            support[base + c1] = (1.f - alpha) * hi1 + alpha * h0[base + c1];
        }
    }
}

// ---------------- K4: out = beta*(support@theta) + (1-beta)*support --------------
__global__ __launch_bounds__(256) void k_out(const float* __restrict__ support,
                                             const float* __restrict__ theta,
                                             float* __restrict__ out,
                                             const float* __restrict__ lamda_p,
                                             const int* __restrict__ l_p) {
    __shared__ __bf16 th[FF * FF];
    __shared__ float  srow[16 * FF];
    int b  = blockIdx.y;
    int r0 = blockIdx.x * 16;
    for (int idx = threadIdx.x; idx < FF * FF; idx += 256) th[idx] = (__bf16)theta[idx];
    for (int idx = threadIdx.x; idx < 16 * FF; idx += 256) {
        int r = idx >> 7;
        int irow = r0 + r;
        srow[idx] = (irow < NN) ? support[((size_t)b * NN + irow) * FF + (idx & 127)] : 0.f;
    }
    __syncthreads();
    float beta = logf(*lamda_p / (float)(*l_p) + 1.0f);
    float omb  = 1.0f - beta;
    int c0 = (threadIdx.x & 31) * 4;
    int rp = (threadIdx.x >> 5) * 2;
    float a0[4] = {0.f, 0.f, 0.f, 0.f};
    float a1[4] = {0.f, 0.f, 0.f, 0.f};
    for (int g = 0; g < FF; ++g) {
        float s0 = srow[rp * FF + g];
        float s1 = srow[rp * FF + FF + g];
        bf16x4 t4 = *(const bf16x4*)&th[g * FF + c0];
        #pragma unroll
        for (int cc = 0; cc < 4; ++cc) {
            float tv = (float)t4[cc];
            a0[cc] += s0 * tv;
            a1[cc] += s1 * tv;
        }
    }
    int irow0 = r0 + rp;
    if (irow0 < NN) {
        float4 o;
        o.x = beta * a0[0] + omb * srow[rp * FF + c0 + 0];
        o.y = beta * a0[1] + omb * srow[rp * FF + c0 + 1];
        o.z = beta * a0[2] + omb * srow[rp * FF + c0 + 2];
        o.w = beta * a0[3] + omb * srow[rp * FF + c0 + 3];
        *(float4*)&out[((size_t)b * NN + irow0) * FF + c0] = o;
    }
    int irow1 = irow0 + 1;
    if (irow1 < NN) {
        float4 o;
        o.x = beta * a1[0] + omb * srow[(rp + 1) * FF + c0 + 0];
        o.y = beta * a1[1] + omb * srow[(rp + 1) * FF + c0 + 1];
        o.z = beta * a1[2] + omb * srow[(rp + 1) * FF + c0 + 2];
        o.w = beta * a1[3] + omb * srow[(rp + 1) * FF + c0 + 3];
        *(float4*)&out[((size_t)b * NN + irow1) * FF + c0] = o;
    }
}

extern "C" void kernel_launch(void* const* d_in, const int* in_sizes, int n_in,
                              void* d_out, int out_size, void* d_ws, size_t ws_size,
                              hipStream_t stream) {
    const float* x      = (const float*)d_in[0];
    const float* adj    = (const float*)d_in[1];
    const float* h0     = (const float*)d_in[2];
    const float* theta  = (const float*)d_in[3];
    const float* lamda  = (const float*)d_in[4];
    const float* alpha  = (const float*)d_in[5];
    const int*   l      = (const int*)d_in[6];
    float* out = (float*)d_out;

    char*   ws      = (char*)d_ws;
    float*  dis     = (float*)ws;                         // 48,000 B
    __bf16* xpk     = (__bf16*)(ws + 65536);              // 4*8*94*512*2 = 3,080,192 B
    float*  support = (float*)(ws + 4 * 1024 * 1024);     // 6,144,000 B

    k_deg<<<dim3((BB * NN) / 4), 256, 0, stream>>>(adj, dis);
    k_xpk<<<dim3(NKC, BB), 256, 0, stream>>>(x, dis, xpk);
    k_agg<<<dim3(NIT, BB), 256, 0, stream>>>(adj, xpk, x, h0, dis, support, alpha);
    k_out<<<dim3(NIT, BB), 256, 0, stream>>>(support, theta, out, lamda, l);
}

// Round 3
// 287.047 us; speedup vs baseline: 1.2170x; 1.0473x over previous
//
#include <hip/hip_runtime.h>
#include <hip/hip_bf16.h>
#include <math.h>

#define BB 4
#define NN 3000
#define FF 128
#define NKC 94          // number of 32-wide K chunks (94*32 = 3008 >= 3000)
#define NIT 188         // number of 16-row tiles (188*16 = 3008)

typedef __bf16 bf16x8 __attribute__((ext_vector_type(8)));
typedef __bf16 bf16x4 __attribute__((ext_vector_type(4)));
typedef float  f32x4  __attribute__((ext_vector_type(4)));

// ---------------- K1: dis[b*NN+i] = 1/sqrt(1 + sum_j adj[b,i,j]) ----------------
__global__ __launch_bounds__(256) void k_deg(const float* __restrict__ adj,
                                             float* __restrict__ dis) {
    int wid  = (blockIdx.x * 256 + threadIdx.x) >> 6;
    int lane = threadIdx.x & 63;
    if (wid >= BB * NN) return;
    const float4* row = (const float4*)(adj + (size_t)wid * NN);
    float s = 0.f;
    for (int c = lane; c < NN / 4; c += 64) {
        float4 v = row[c];
        s += (v.x + v.y) + (v.z + v.w);
    }
    for (int off = 32; off > 0; off >>= 1) s += __shfl_down(s, off, 64);
    if (lane == 0) dis[wid] = 1.0f / sqrtf(s + 1.0f);
}

// ---------------- K2: pack xs = dis_k * x[k][f] into MFMA B-fragment order ------
// xpk[b][nt][kc][lane][8], lane = (f%16) + 16*quad, k = kc*32 + quad*8 + j.
__global__ __launch_bounds__(256) void k_xpk(const float* __restrict__ x,
                                             const float* __restrict__ dis,
                                             __bf16* __restrict__ xpk) {
    int b  = blockIdx.y, kc = blockIdx.x;
    int t  = threadIdx.x, w = t >> 6, l = t & 63;
    int m  = l & 15, q = l >> 4;
    #pragma unroll
    for (int h = 0; h < 2; ++h) {
        int nt = w + h * 4;
        int f  = nt * 16 + m;
        bf16x8 v;
        #pragma unroll
        for (int j = 0; j < 8; ++j) {
            int k = kc * 32 + q * 8 + j;
            float val = 0.f;
            if (k < NN) val = dis[b * NN + k] * x[((size_t)b * NN + k) * FF + f];
            v[j] = (__bf16)val;
        }
        *(bf16x8*)(xpk + ((size_t)(b * 8 + nt) * NKC + kc) * 512 + l * 8) = v;
    }
}

// ---------------- K2b: pack theta into MFMA B-fragment order --------------------
// thpk[nt][kc][lane][8] = theta[k = kc*32+quad*8+j][g = nt*16 + (lane&15)], bf16.
__global__ __launch_bounds__(256) void k_thpk(const float* __restrict__ theta,
                                              __bf16* __restrict__ thpk) {
    int kc = blockIdx.x;
    int t  = threadIdx.x, w = t >> 6, l = t & 63;
    int m  = l & 15, q = l >> 4;
    #pragma unroll
    for (int h = 0; h < 2; ++h) {
        int nt = w + h * 4;
        bf16x8 v;
        #pragma unroll
        for (int j = 0; j < 8; ++j) {
            int k = kc * 32 + q * 8 + j;
            v[j] = (__bf16)theta[k * FF + nt * 16 + m];
        }
        *(bf16x8*)(thpk + ((size_t)(nt * 4 + kc)) * 512 + l * 8) = v;
    }
}

// ---------------- K3 (fused): out = beta*(support@theta) + (1-beta)*support ------
// support = (1-alpha)*hi + alpha*h0,  hi_i = dis_i*(adj_i . xs) + dis_i^2 * x_i
// Block: 16 rows x 128 cols, 4 waves. A (adj) staged via LDS; B pre-packed.
// Epilogue: support tile -> LDS (bf16, A-layout) -> 8 MFMA vs thpk -> blend+store.
__global__ __launch_bounds__(256) void k_agg(const float* __restrict__ adj,
                                             const __bf16* __restrict__ xpk,
                                             const __bf16* __restrict__ thpk,
                                             const float* __restrict__ x,
                                             const float* __restrict__ h0,
                                             const float* __restrict__ dis,
                                             float* __restrict__ out,
                                             const float* __restrict__ alpha_p,
                                             const float* __restrict__ lamda_p,
                                             const int* __restrict__ l_p) {
    __shared__ __bf16 tile[16][264];   // K-chunk staging; reused for support tile
    const int b  = blockIdx.y;
    const int i0 = blockIdx.x * 16;
    const int t  = threadIdx.x, w = t >> 6, l = t & 63;
    const int m  = l & 15, quad = l >> 4;
    const int n0 = w * 32;
    const __bf16* B0 = xpk + ((size_t)(b * 8 + 2 * w) * NKC) * 512 + l * 8;
    const __bf16* B1 = B0 + (size_t)NKC * 512;
    f32x4 acc0 = {0.f, 0.f, 0.f, 0.f};
    f32x4 acc1 = {0.f, 0.f, 0.f, 0.f};
    for (int c = 0; c < 12; ++c) {
        int k0 = c * 256;
        #pragma unroll
        for (int i = 0; i < 4; ++i) {
            int row = i * 4 + w;
            int col = k0 + l * 4;
            float4 v = {0.f, 0.f, 0.f, 0.f};
            if (i0 + row < NN && col < NN)
                v = *(const float4*)(adj + ((size_t)b * NN + i0 + row) * NN + col);
            __bf16* tp = &tile[row][l * 4];
            tp[0] = (__bf16)v.x; tp[1] = (__bf16)v.y;
            tp[2] = (__bf16)v.z; tp[3] = (__bf16)v.w;
        }
        __syncthreads();
        int nk = (c == 11) ? 6 : 8;   // last chunk: kc 88..93
        #pragma unroll 2
        for (int kcl = 0; kcl < nk; ++kcl) {
            int kc = c * 8 + kcl;
            bf16x8 a  = *(const bf16x8*)&tile[m][kcl * 32 + quad * 8];
            bf16x8 b0 = *(const bf16x8*)(B0 + (size_t)kc * 512);
            bf16x8 b1 = *(const bf16x8*)(B1 + (size_t)kc * 512);
            acc0 = __builtin_amdgcn_mfma_f32_16x16x32_bf16(a, b0, acc0, 0, 0, 0);
            acc1 = __builtin_amdgcn_mfma_f32_16x16x32_bf16(a, b1, acc1, 0, 0, 0);
        }
        __syncthreads();
    }
    // ---- epilogue: support values + stage into LDS in A-layout (bf16) ----
    const float alpha = *alpha_p;
    const float beta  = logf(*lamda_p / (float)(*l_p) + 1.0f);
    float s0v[4], s1v[4];
    #pragma unroll
    for (int r = 0; r < 4; ++r) {
        int row  = quad * 4 + r;
        int irow = i0 + row;
        float s0 = 0.f, s1 = 0.f;
        if (irow < NN) {
            float  di   = dis[b * NN + irow];
            size_t base = ((size_t)b * NN + irow) * FF;
            int c0 = n0 + m, c1 = n0 + 16 + m;
            s0 = (1.f - alpha) * (di * acc0[r] + di * di * x[base + c0]) + alpha * h0[base + c0];
            s1 = (1.f - alpha) * (di * acc1[r] + di * di * x[base + c1]) + alpha * h0[base + c1];
        }
        s0v[r] = s0; s1v[r] = s1;
        tile[row][n0 + m]      = (__bf16)s0;
        tile[row][n0 + 16 + m] = (__bf16)s1;
    }
    __syncthreads();
    // ---- theta matmul on the 16x128 support tile ----
    f32x4 o0 = {0.f, 0.f, 0.f, 0.f};
    f32x4 o1 = {0.f, 0.f, 0.f, 0.f};
    const __bf16* T0 = thpk + (size_t)(2 * w * 4) * 512 + l * 8;
    const __bf16* T1 = T0 + 4 * 512;
    #pragma unroll
    for (int kc = 0; kc < 4; ++kc) {
        bf16x8 a   = *(const bf16x8*)&tile[m][kc * 32 + quad * 8];
        bf16x8 tb0 = *(const bf16x8*)(T0 + (size_t)kc * 512);
        bf16x8 tb1 = *(const bf16x8*)(T1 + (size_t)kc * 512);
        o0 = __builtin_amdgcn_mfma_f32_16x16x32_bf16(a, tb0, o0, 0, 0, 0);
        o1 = __builtin_amdgcn_mfma_f32_16x16x32_bf16(a, tb1, o1, 0, 0, 0);
    }
    const float omb = 1.f - beta;
    #pragma unroll
    for (int r = 0; r < 4; ++r) {
        int irow = i0 + quad * 4 + r;
        if (irow < NN) {
            size_t base = ((size_t)b * NN + irow) * FF;
            out[base + n0 + m]      = beta * o0[r] + omb * s0v[r];
            out[base + n0 + 16 + m] = beta * o1[r] + omb * s1v[r];
        }
    }
}

extern "C" void kernel_launch(void* const* d_in, const int* in_sizes, int n_in,
                              void* d_out, int out_size, void* d_ws, size_t ws_size,
                              hipStream_t stream) {
    const float* x      = (const float*)d_in[0];
    const float* adj    = (const float*)d_in[1];
    const float* h0     = (const float*)d_in[2];
    const float* theta  = (const float*)d_in[3];
    const float* lamda  = (const float*)d_in[4];
    const float* alpha  = (const float*)d_in[5];
    const int*   l      = (const int*)d_in[6];
    float* out = (float*)d_out;

    char*   ws   = (char*)d_ws;
    float*  dis  = (float*)ws;                 // 48,000 B
    __bf16* xpk  = (__bf16*)(ws + 65536);      // 4*8*94*512*2 = 3,080,192 B
    __bf16* thpk = (__bf16*)(ws + 3200000);    // 8*4*512*2 = 32,768 B

    k_deg<<<dim3((BB * NN) / 4), 256, 0, stream>>>(adj, dis);
    k_xpk<<<dim3(NKC, BB), 256, 0, stream>>>(x, dis, xpk);
    k_thpk<<<dim3(4), 256, 0, stream>>>(theta, thpk);
    k_agg<<<dim3(NIT, BB), 256, 0, stream>>>(adj, xpk, thpk, x, h0, dis, out,
                                             alpha, lamda, l);
}